// Round 4
// baseline (654.807 us; speedup 1.0000x reference)
//
#include <hip/hip_runtime.h>
#include <cstdint>

// Anchor3DHead fused 1x1-conv heads, R6: async global->LDS x-staging with
// counted vmcnt (T3/T4 pattern). R3-R5 proved register-level prefetch is a
// dead end at HIP source (compiler fission / VALU copy overhead). Here the
// x tile moves via global_load_lds_dwordx4 (no VGPR round-trip, no VALU),
// 2 chunks deep, with s_waitcnt vmcnt(2) + raw s_barrier so loads stay in
// flight across barriers. Weights are wave-uniform -> s_load (lgkmcnt), so
// vmcnt counts ONLY the staging loads.
// Block = 256 thr = 4 waves = 64 pixels. Chunk = 16 channels:
//   stage: wave w loads channels w*4+(lane>>4), pixels (lane&15)*4..+3
//          -> one global_load_lds_dwordx4 per wave per chunk (1 KB).
//   compute: wave w's 18 output channels x 16 chunk-channels = 288 FMAs.
// Roles: w0 cls[0..18) | w1 reg[0..18) | w2 reg[18..36) | w3 reg[36..42)+dir.
// Barriers are at kernel scope (uniform); only the FMA body is role-branched.

constexpr int Bn   = 4;
constexpr int Cc   = 384;
constexpr int Hh   = 248;
constexpr int Ww   = 216;
constexpr int HW   = Hh * Ww;          // 53568 (div by 64 and 16)
constexpr int NPIX = Bn * HW;          // 214272 = 64 * 3348
constexpr int NCLS = 18;
constexpr int NREG = 42;
constexpr int NDIR = 12;
constexpr int CH     = 16;             // channels per staged chunk
constexpr int NCHUNK = Cc / CH;        // 24

typedef const __attribute__((address_space(1))) void* as1cp;
typedef __attribute__((address_space(3))) void*       as3p;

// One chunk of FMAs for one wave role: NA outputs from wA (row stride LDA),
// NB outputs from wB (stride LDB). Weight addresses contain no threadIdx ->
// uniform -> scalar loads. x comes from the staged LDS tile.
template<int NA, int LDA, int NB, int LDB>
__device__ __forceinline__ void chunk_fma(
    float (&acc)[18], const float (*xc)[64], const int lane,
    const float* __restrict__ wA, const float* __restrict__ wB)
{
    #pragma unroll
    for (int c = 0; c < CH; ++c) {
        const float xv = xc[c][lane];
        #pragma unroll
        for (int j = 0; j < NA; ++j)
            acc[j] = fmaf(xv, wA[c * LDA + j], acc[j]);
        #pragma unroll
        for (int j = 0; j < NB; ++j)
            acc[NA + j] = fmaf(xv, wB[c * LDB + j], acc[NA + j]);
    }
}

__global__ __launch_bounds__(256) void head_fused_lds(
    const float* __restrict__ x,
    const float* __restrict__ wc, const float* __restrict__ bc,
    const float* __restrict__ wr, const float* __restrict__ br,
    const float* __restrict__ wd, const float* __restrict__ bd,
    float* __restrict__ out)
{
    __shared__ float xs[3][CH][64];    // 12 KB, triple-buffered chunk tiles

    const int w    = threadIdx.x >> 6;       // wave id 0..3 (uniform per wave)
    const int lane = threadIdx.x & 63;
    const int w4   = w << 2;
    const int pb   = blockIdx.x * 64;        // block pixel base (HW % 64 == 0)
    const int b    = pb / HW;                // uniform per block
    const int p    = pb - b * HW;            // multiple of 64

    // per-lane staging source: channel w4+(lane>>4), pixel p+(lane&15)*4
    const float* xrow = x + (size_t)b * Cc * HW + p;
    const float* xg   = xrow + (size_t)(w4 + (lane >> 4)) * HW + (lane & 15) * 4;

    float* outc = out + (size_t)b * NCLS * HW + p + lane;
    float* outr = out + (size_t)Bn * NCLS * HW + (size_t)b * NREG * HW + p + lane;
    float* outd = out + (size_t)Bn * (NCLS + NREG) * HW
                      + (size_t)b * NDIR * HW + p + lane;

    // accumulator init (bias); every role has exactly 18 outputs
    float acc[18];
    if (w == 0) {
        #pragma unroll
        for (int j = 0; j < 18; ++j) acc[j] = bc[j];
    } else if (w == 1) {
        #pragma unroll
        for (int j = 0; j < 18; ++j) acc[j] = br[j];
    } else if (w == 2) {
        #pragma unroll
        for (int j = 0; j < 18; ++j) acc[j] = br[18 + j];
    } else {
        #pragma unroll
        for (int j = 0; j < 6; ++j)  acc[j] = br[36 + j];
        #pragma unroll
        for (int j = 0; j < 12; ++j) acc[6 + j] = bd[j];
    }

    // prologue: chunks 0 and 1 in flight (1 load-instr per wave per chunk)
    __builtin_amdgcn_global_load_lds((as1cp)xg,
                                     (as3p)&xs[0][w4][0], 16, 0, 0);
    __builtin_amdgcn_global_load_lds((as1cp)(xg + (size_t)CH * HW),
                                     (as3p)&xs[1][w4][0], 16, 0, 0);

    int bs = 0;                              // buffer holding chunk t
    #pragma unroll 1
    for (int t = 0; t < NCHUNK; ++t) {
        if (t + 2 < NCHUNK) {
            const int bf = (bs + 2 >= 3) ? bs - 1 : bs + 2;
            __builtin_amdgcn_global_load_lds(
                (as1cp)(xg + (size_t)(t + 2) * CH * HW),
                (as3p)&xs[bf][w4][0], 16, 0, 0);
            // counted wait: chunks t+1, t+2 remain in flight across barrier
            asm volatile("s_waitcnt vmcnt(2)" ::: "memory");
        } else if (t + 2 == NCHUNK) {
            asm volatile("s_waitcnt vmcnt(1)" ::: "memory");
        } else {
            asm volatile("s_waitcnt vmcnt(0)" ::: "memory");
        }
        __builtin_amdgcn_s_barrier();        // chunk t visible to all waves

        const float* xc0 = &xs[bs][0][0];
        const float (*xc)[64] = (const float (*)[64])xc0;
        if (w == 0) {
            chunk_fma<18, NCLS, 0, 1>(acc, xc, lane,
                                      wc + (size_t)t * CH * NCLS, wc);
        } else if (w == 1) {
            chunk_fma<18, NREG, 0, 1>(acc, xc, lane,
                                      wr + (size_t)t * CH * NREG, wr);
        } else if (w == 2) {
            chunk_fma<18, NREG, 0, 1>(acc, xc, lane,
                                      wr + 18 + (size_t)t * CH * NREG, wr);
        } else {
            chunk_fma<6, NREG, 12, NDIR>(acc, xc, lane,
                                         wr + 36 + (size_t)t * CH * NREG,
                                         wd + (size_t)t * CH * NDIR);
        }

        // no wave may stage chunk t+3 (same buffer) until all finished reading
        if (t + 1 < NCHUNK) __builtin_amdgcn_s_barrier();
        bs = (bs + 1 == 3) ? 0 : bs + 1;
    }

    // epilogue: coalesced stores (256 B per wave-instr per output channel)
    if (w == 0) {
        #pragma unroll
        for (int j = 0; j < 18; ++j) outc[(size_t)j * HW] = acc[j];
    } else if (w == 1) {
        #pragma unroll
        for (int j = 0; j < 18; ++j) outr[(size_t)j * HW] = acc[j];
    } else if (w == 2) {
        #pragma unroll
        for (int j = 0; j < 18; ++j) outr[(size_t)(18 + j) * HW] = acc[j];
    } else {
        #pragma unroll
        for (int j = 0; j < 6; ++j)  outr[(size_t)(36 + j) * HW] = acc[j];
        #pragma unroll
        for (int j = 0; j < 12; ++j) outd[(size_t)j * HW] = acc[6 + j];
    }
}

extern "C" void kernel_launch(void* const* d_in, const int* in_sizes, int n_in,
                              void* d_out, int out_size, void* d_ws, size_t ws_size,
                              hipStream_t stream) {
    const float* x  = (const float*)d_in[0];
    const float* wc = (const float*)d_in[1];
    const float* bc = (const float*)d_in[2];
    const float* wr = (const float*)d_in[3];
    const float* br = (const float*)d_in[4];
    const float* wd = (const float*)d_in[5];
    const float* bd = (const float*)d_in[6];
    float* out = (float*)d_out;

    dim3 grid(NPIX / 64);    // 3348 blocks, exact cover
    dim3 block(256);
    head_fused_lds<<<grid, block, 0, stream>>>(x, wc, bc, wr, br, wd, bd, out);
}